// Round 3
// baseline (222.401 us; speedup 1.0000x reference)
//
#include <hip/hip_runtime.h>
#include <hip/hip_bf16.h>

typedef __bf16 bf16_t;
typedef __bf16 bf16x8 __attribute__((ext_vector_type(8)));
typedef float f32x4 __attribute__((ext_vector_type(4)));
typedef short short4v __attribute__((ext_vector_type(4)));
typedef unsigned int uint2v __attribute__((ext_vector_type(2)));

#define D_MODEL 1024
#define T_SEQ 2048
#define NH 16
#define DKD 64
#define X_ELEMS (4194304u)   // 2*2048*1024
#define W_ELEMS (1048576u)   // 1024*1024
// 0.125 * log2(e): folds the 1/sqrt(dk) scale AND the exp->exp2 conversion into Q
#define Q_SCALE 0.18033688011112042f

__device__ __forceinline__ void async16(const bf16_t* g, bf16_t* l) {
    __builtin_amdgcn_global_load_lds((const __attribute__((address_space(1))) void*)g,
                                     (__attribute__((address_space(3))) void*)l, 16, 0, 0);
}

// ---------------- fp32 -> bf16 conversion for x + 4 weights ----------------
__global__ __launch_bounds__(256) void convert_kernel(
    const float* __restrict__ x, const float* __restrict__ wq,
    const float* __restrict__ wk, const float* __restrict__ wv,
    const float* __restrict__ wo,
    bf16_t* __restrict__ xb, bf16_t* __restrict__ wqb, bf16_t* __restrict__ wkb,
    bf16_t* __restrict__ wvb, bf16_t* __restrict__ wob)
{
    size_t idx = ((size_t)blockIdx.x * 256 + threadIdx.x) * 4;
    const float* src; bf16_t* dst; size_t off;
    if (idx < X_ELEMS) { src = x; dst = xb; off = idx; }
    else {
        size_t r = idx - X_ELEMS;
        unsigned w = (unsigned)(r >> 20);
        off = r & (W_ELEMS - 1);
        src = (w == 0) ? wq : (w == 1) ? wk : (w == 2) ? wv : wo;
        dst = (w == 0) ? wqb : (w == 1) ? wkb : (w == 2) ? wvb : wob;
    }
    float4 v = *(const float4*)(src + off);
    union { bf16_t b[4]; short4v s; } u;
    u.b[0] = (bf16_t)v.x; u.b[1] = (bf16_t)v.y;
    u.b[2] = (bf16_t)v.z; u.b[3] = (bf16_t)v.w;
    *(short4v*)(dst + off) = u.s;
}

// ---------------- RoPE cos/sin tables: [T][32] ----------------
__global__ __launch_bounds__(256) void rope_kernel(float* __restrict__ cost, float* __restrict__ sint)
{
    int idx = blockIdx.x * 256 + threadIdx.x;  // < 2048*32
    int t = idx >> 5, i = idx & 31;
    float inv = expf(-0.28782313662425572f * (float)i);  // 10000^(-i/32)
    float ang = (float)t * inv;
    float s, c;
    sincosf(ang, &s, &c);
    cost[idx] = c; sint[idx] = s;
}

// ---------------- GEMM C[m,n] = sum_k A[m,k]*W[n,k]  (m97 structure) ----------------
// mode 0: Q out (rope, *Q_SCALE, (B,H,T,DK) bf16)   mode 1: K out (rope, (B,H,T,DK) bf16)
// mode 2: V^T out (B,H,DK,T) bf16 — SWAPPED operands so C/D col (lane&15) = token.
// mode 3: plain fp32 out [M,N]
__global__ __launch_bounds__(256) void gemm_fused(
    const bf16_t* __restrict__ A,
    const bf16_t* __restrict__ W0, const bf16_t* __restrict__ W1, const bf16_t* __restrict__ W2,
    bf16_t* __restrict__ qout, bf16_t* __restrict__ kout, bf16_t* __restrict__ vout,
    const float* __restrict__ cost, const float* __restrict__ sint,
    float* __restrict__ fout, int modeBase)
{
    const int K = 1024;
    __shared__ bf16_t As[128 * 32];
    __shared__ bf16_t Bs[128 * 32];
    const int tid = threadIdx.x;
    const int wave = tid >> 6, lane = tid & 63;
    const int quad = lane >> 4, l16 = lane & 15;
    const int m0 = blockIdx.x * 128;
    const int n0 = blockIdx.y * 128;
    const int wm = (wave >> 1) * 64, wn = (wave & 1) * 64;
    const int mode = modeBase + blockIdx.z;
    const bf16_t* W = (mode == 1) ? W1 : (mode == 2) ? W2 : W0;

    const bf16_t* Afrag = (mode == 2) ? Bs : As;
    const bf16_t* Bfrag = (mode == 2) ? As : Bs;
    const int aoff = (mode == 2) ? wn : wm;
    const int boff = (mode == 2) ? wm : wn;

    const f32x4 fzero = {0.f, 0.f, 0.f, 0.f};
    f32x4 acc[4][4];
    #pragma unroll
    for (int i = 0; i < 4; ++i)
        #pragma unroll
        for (int j = 0; j < 4; ++j) acc[i][j] = fzero;

    for (int k0 = 0; k0 < K; k0 += 32) {
        __syncthreads();
        #pragma unroll
        for (int c = 0; c < 2; ++c) {
            int G = c * 256 + tid;
            int row = G >> 2, go = G & 3;
            async16(A + (size_t)(m0 + row) * K + (k0 + go * 8), As + (size_t)(c * 256 + wave * 64) * 8);
            async16(W + (size_t)(n0 + row) * K + (k0 + go * 8), Bs + (size_t)(c * 256 + wave * 64) * 8);
        }
        __syncthreads();
        bf16x8 af[4], bfv[4];
        #pragma unroll
        for (int mi = 0; mi < 4; ++mi)
            af[mi] = *(const bf16x8*)(Afrag + (aoff + mi * 16 + l16) * 32 + quad * 8);
        #pragma unroll
        for (int ni = 0; ni < 4; ++ni)
            bfv[ni] = *(const bf16x8*)(Bfrag + (boff + ni * 16 + l16) * 32 + quad * 8);
        #pragma unroll
        for (int mi = 0; mi < 4; ++mi)
            #pragma unroll
            for (int ni = 0; ni < 4; ++ni)
                acc[mi][ni] = __builtin_amdgcn_mfma_f32_16x16x32_bf16(af[mi], bfv[ni], acc[mi][ni], 0, 0, 0);
    }

    #pragma unroll
    for (int mi = 0; mi < 4; ++mi) {
        #pragma unroll
        for (int ni = 0; ni < 4; ++ni) {
            #pragma unroll
            for (int reg = 0; reg < 4; ++reg) {
                float v = acc[mi][ni][reg];
                if (mode == 2) {
                    int f   = n0 + wn + mi * 16 + quad * 4 + reg;
                    int tok = m0 + wm + ni * 16 + l16;
                    int t = tok & (T_SEQ - 1), b = tok >> 11;
                    int h = f >> 6, dk = f & 63;
                    vout[(((size_t)b * NH + h) * DKD + dk) * T_SEQ + t] = (bf16_t)v;
                } else {
                    int row = m0 + wm + mi * 16 + quad * 4 + reg;
                    int col = n0 + wn + ni * 16 + l16;
                    if (mode == 3) {
                        fout[(size_t)row * D_MODEL + col] = v;
                    } else {
                        int t = row & (T_SEQ - 1), b = row >> 11;
                        int h = col >> 6, dk = col & 63;
                        float vp = __shfl_xor(v, 1);
                        int fi = dk >> 1;
                        float c = cost[t * 32 + fi], s = sint[t * 32 + fi];
                        float r = (dk & 1) ? (vp * s + v * c) : (v * c - vp * s);
                        if (mode == 0) r *= Q_SCALE;   // fold 1/sqrt(dk)*log2e into Q
                        bf16_t* dst = (mode == 0) ? qout : kout;
                        dst[(((size_t)b * NH + h) * T_SEQ + t) * DKD + dk] = (bf16_t)r;
                    }
                }
            }
        }
    }
}

// ---------------- flash attention: split-K balanced, LDS-free ----------------
// Fixed-shift base-2 softmax (Q pre-scaled by 0.125*log2e) => partials over
// disjoint key ranges are ADDITIVE: O = sum O_c, l = sum l_c. Used to balance
// the causal triangle: q-tiles y>=32 split into key chunks [0,16) and
// [16,nkt) handled by independent waves writing fp32 partials; combine_kernel
// reduces them. Critical path 32 -> ~17 k-tiles; waves 2048 -> 3072.
//
// P^T for the PV MFMA is built IN-REGISTER: v_cvt_pk_bf16_f32 pairs +
// v_permlane16_swap_b32 (A'=(Ar0,Br0,Ar2,Br2), B'=(Ar1,Br1,Ar3,Br3)) regroup
// quads; the induced 8-key-block permutation sigma=(0,2,1,3) is absorbed into
// the V fragment load offset. No LDS at all -> bank conflicts and the
// ds-roundtrip latency disappear from the serial chain.
//
// Block map (blockIdx.y = u, heavy-first):
//   u in [0,32)  : y = u+32 (qw>=1024), chunk0 = tiles [0,16)   (16 tiles, no mask)
//   u in [32,64) : y = 95-u (63..32),   chunk1 = tiles [16,nkt) (16..1 tiles, diag)
//   u in [64,96) : y = 95-u (31..0),    single = tiles [0,nkt)  (16..1 tiles)
__global__ __launch_bounds__(64, 2) void attn_kernel(
    const bf16_t* __restrict__ Q, const bf16_t* __restrict__ Kb,
    const bf16_t* __restrict__ Vt, bf16_t* __restrict__ O,
    float* __restrict__ Opart, float* __restrict__ Lpart)
{
    const int lane = threadIdx.x;
    const int quad = lane >> 4, l16 = lane & 15;
    const int vq = (((quad & 1) << 1) | (quad >> 1)) * 8;   // sigma(quad)*8: permuted V key base
    const int bh = blockIdx.x;
    const int u = blockIdx.y;
    int y, ktlo, kthi;
    if (u < 32) { y = u + 32; ktlo = 0; kthi = 16; }
    else { y = 95 - u; ktlo = (u < 64) ? 16 : 0; kthi = (y * 32 + 95) >> 6; }
    const int qw = y * 32;

    const bf16_t* kbase = Kb + (size_t)bh * T_SEQ * DKD;
    const bf16_t* vbase = Vt + (size_t)bh * DKD * T_SEQ;

    // Q^T B-frags: n=l16 (query), k=quad*8+j (+32)
    bf16x8 qf[2][2];
    #pragma unroll
    for (int j = 0; j < 2; ++j) {
        const bf16_t* qp = Q + ((size_t)bh * T_SEQ + qw + j * 16 + l16) * DKD;
        qf[j][0] = *(const bf16x8*)(qp + quad * 8);
        qf[j][1] = *(const bf16x8*)(qp + 32 + quad * 8);
    }
    const f32x4 fzero = {0.f, 0.f, 0.f, 0.f};
    f32x4 oacc[2][4];
    #pragma unroll
    for (int j = 0; j < 2; ++j)
        #pragma unroll
        for (int i = 0; i < 4; ++i) oacc[j][i] = fzero;
    float lsum[2] = {0.f, 0.f};   // in-lane partial softmax denominator

    bf16x8 ka[4][2], kb2[4][2], vcur[4][2];
    #pragma unroll
    for (int fi = 0; fi < 4; ++fi) {
        const bf16_t* kr = kbase + (size_t)(ktlo * 64 + fi * 16 + l16) * DKD + quad * 8;
        ka[fi][0] = *(const bf16x8*)(kr);
        ka[fi][1] = *(const bf16x8*)(kr + 32);
    }

#define ATT_TILE(KC, KN) do { \
    const int k0 = kt * 64; \
    _Pragma("unroll") \
    for (int di = 0; di < 4; ++di) { \
        const bf16_t* vr = vbase + (size_t)(di * 16 + l16) * T_SEQ + k0 + vq; \
        vcur[di][0] = *(const bf16x8*)(vr); \
        vcur[di][1] = *(const bf16x8*)(vr + 32); \
    } \
    if (kt + 1 < kthi) { \
        _Pragma("unroll") \
        for (int fi = 0; fi < 4; ++fi) { \
            const bf16_t* kr = kbase + (size_t)(k0 + 64 + fi * 16 + l16) * DKD + quad * 8; \
            KN[fi][0] = *(const bf16x8*)(kr); \
            KN[fi][1] = *(const bf16x8*)(kr + 32); \
        } \
    } \
    _Pragma("unroll") \
    for (int j = 0; j < 2; ++j) { \
        if (k0 > qw + j * 16 + 15) continue;   /* q-tile fully masked */ \
        const int qcol = qw + j * 16 + l16; \
        f32x4 s[4]; \
        _Pragma("unroll") \
        for (int fi = 0; fi < 4; ++fi) { \
            f32x4 z = fzero; \
            z = __builtin_amdgcn_mfma_f32_16x16x32_bf16(KC[fi][0], qf[j][0], z, 0, 0, 0); \
            z = __builtin_amdgcn_mfma_f32_16x16x32_bf16(KC[fi][1], qf[j][1], z, 0, 0, 0); \
            s[fi] = z; \
        } \
        if (k0 + 63 > qw + j * 16) { \
            _Pragma("unroll") \
            for (int fi = 0; fi < 4; ++fi) \
                _Pragma("unroll") \
                for (int reg = 0; reg < 4; ++reg) { \
                    int key = k0 + fi * 16 + quad * 4 + reg; \
                    s[fi][reg] = (key > qcol) ? -__builtin_inff() : s[fi][reg]; \
                } \
        } \
        float sm = 0.f; \
        _Pragma("unroll") \
        for (int fi = 0; fi < 4; ++fi) \
            _Pragma("unroll") \
            for (int reg = 0; reg < 4; ++reg) { \
                float p = __builtin_amdgcn_exp2f(s[fi][reg]); \
                s[fi][reg] = p; sm += p; \
            } \
        lsum[j] += sm; \
        unsigned wv[4][2]; \
        _Pragma("unroll") \
        for (int fi = 0; fi < 4; ++fi) { \
            asm("v_cvt_pk_bf16_f32 %0, %1, %2" : "=v"(wv[fi][0]) : "v"(s[fi][0]), "v"(s[fi][1])); \
            asm("v_cvt_pk_bf16_f32 %0, %1, %2" : "=v"(wv[fi][1]) : "v"(s[fi][2]), "v"(s[fi][3])); \
        } \
        uint2v r0 = __builtin_amdgcn_permlane16_swap(wv[0][0], wv[1][0], false, false); \
        uint2v r1 = __builtin_amdgcn_permlane16_swap(wv[0][1], wv[1][1], false, false); \
        uint2v r2 = __builtin_amdgcn_permlane16_swap(wv[2][0], wv[3][0], false, false); \
        uint2v r3 = __builtin_amdgcn_permlane16_swap(wv[2][1], wv[3][1], false, false); \
        union { unsigned uu[4]; bf16x8 v; } p0, p1; \
        p0.uu[0] = r0[0]; p0.uu[1] = r1[0]; p0.uu[2] = r0[1]; p0.uu[3] = r1[1]; \
        p1.uu[0] = r2[0]; p1.uu[1] = r3[0]; p1.uu[2] = r2[1]; p1.uu[3] = r3[1]; \
        _Pragma("unroll") \
        for (int di = 0; di < 4; ++di) { \
            oacc[j][di] = __builtin_amdgcn_mfma_f32_16x16x32_bf16(vcur[di][0], p0.v, oacc[j][di], 0, 0, 0); \
            oacc[j][di] = __builtin_amdgcn_mfma_f32_16x16x32_bf16(vcur[di][1], p1.v, oacc[j][di], 0, 0, 0); \
        } \
    } \
} while (0)

    bool flip = false;
    for (int kt = ktlo; kt < kthi; ++kt) {
        if (!flip) { ATT_TILE(ka, kb2); } else { ATT_TILE(kb2, ka); }
        flip = !flip;
    }
#undef ATT_TILE

    if (u >= 64) {
        // single-chunk: cross-quad l reduction, scale, store bf16 directly
        const int b = bh >> 4, h = bh & 15;
        #pragma unroll
        for (int j = 0; j < 2; ++j) {
            float l = lsum[j];
            l += __shfl_xor(l, 16);
            l += __shfl_xor(l, 32);
            float rl = 1.0f / l;
            int q = qw + j * 16 + l16;
            #pragma unroll
            for (int di = 0; di < 4; ++di) {
                union { bf16_t hh[4]; unsigned long long u64; } ok;
                #pragma unroll
                for (int reg = 0; reg < 4; ++reg) ok.hh[reg] = (bf16_t)(oacc[j][di][reg] * rl);
                int d = di * 16 + quad * 4;
                *(unsigned long long*)(O + ((size_t)b * T_SEQ + q) * D_MODEL + h * DKD + d) = ok.u64;
            }
        }
    } else {
        // partial: raw fp32 oacc + per-lane lsum to workspace (coalesced 16B stores)
        const int yy = y - 32;
        const int chunk = (ktlo == 16) ? 1 : 0;
        const size_t slot = ((size_t)bh * 32 + yy) * 2 + chunk;
        float* op = Opart + slot * 2048;
        #pragma unroll
        for (int j = 0; j < 2; ++j) {
            Lpart[slot * 128 + j * 64 + lane] = lsum[j];
            #pragma unroll
            for (int di = 0; di < 4; ++di)
                *(f32x4*)(op + ((size_t)(j * 4 + di) * 64 + lane) * 4) = oacc[j][di];
        }
    }
}

// ---------------- combine: O = (O_c0 + O_c1) / (l_c0 + l_c1), upper half only ----------------
__global__ __launch_bounds__(256) void combine_kernel(
    const float* __restrict__ Opart, const float* __restrict__ Lpart, bf16_t* __restrict__ O)
{
    const int bh = blockIdx.x, yy = blockIdx.y;
    const int t = threadIdx.x;
    const int ql = t >> 3;             // 0..31 local query
    const int d0 = (t & 7) * 8;        // 0,8,...,56
    const int j = ql >> 4, l16 = ql & 15;
    const size_t a = (size_t)bh * 32 + yy;
    const float* A0 = Opart + a * 2 * 2048;
    const float* A1 = A0 + 2048;
    const float* L = Lpart + a * 2 * 128 + j * 64 + l16;
    float l = 0.f;
    #pragma unroll
    for (int q = 0; q < 4; ++q) l += L[q * 16] + L[128 + q * 16];
    const float rl = 1.0f / l;
    const int di = d0 >> 4;
    const int quad0 = (d0 & 15) >> 2;  // 0 or 2
    union { bf16_t h[8]; bf16x8 v; } ov;
    #pragma unroll
    for (int g = 0; g < 2; ++g) {
        const int off = ((j * 4 + di) * 64 + (quad0 + g) * 16 + l16) * 4;
        f32x4 x0 = *(const f32x4*)(A0 + off);
        f32x4 x1 = *(const f32x4*)(A1 + off);
        #pragma unroll
        for (int reg = 0; reg < 4; ++reg)
            ov.h[g * 4 + reg] = (bf16_t)((x0[reg] + x1[reg]) * rl);
    }
    const int b = bh >> 4, h = bh & 15;
    const int q = 1024 + yy * 32 + ql;
    *(bf16x8*)(O + ((size_t)b * T_SEQ + q) * D_MODEL + h * DKD + d0) = ov.v;
}

extern "C" void kernel_launch(void* const* d_in, const int* in_sizes, int n_in,
                              void* d_out, int out_size, void* d_ws, size_t ws_size,
                              hipStream_t stream)
{
    const float* x  = (const float*)d_in[0];
    const float* wq = (const float*)d_in[1];
    const float* wk = (const float*)d_in[2];
    const float* wv = (const float*)d_in[3];
    const float* wo = (const float*)d_in[4];
    float* out = (float*)d_out;

    char* ws = (char*)d_ws;
    size_t off = 0;
    auto alloc = [&](size_t bytes) -> void* {
        void* p = ws + off; off += (bytes + 255) & ~(size_t)255; return p;
    };
    bf16_t* xb   = (bf16_t*)alloc((size_t)X_ELEMS * 2);
    bf16_t* wqb  = (bf16_t*)alloc((size_t)W_ELEMS * 2);
    bf16_t* wkb  = (bf16_t*)alloc((size_t)W_ELEMS * 2);
    bf16_t* wvb  = (bf16_t*)alloc((size_t)W_ELEMS * 2);
    bf16_t* wob  = (bf16_t*)alloc((size_t)W_ELEMS * 2);
    bf16_t* qb   = (bf16_t*)alloc((size_t)X_ELEMS * 2);
    bf16_t* kb   = (bf16_t*)alloc((size_t)X_ELEMS * 2);
    bf16_t* vtb  = (bf16_t*)alloc((size_t)X_ELEMS * 2);
    bf16_t* ob   = (bf16_t*)alloc((size_t)X_ELEMS * 2);
    float*  cost = (float*)alloc((size_t)T_SEQ * 32 * 4);
    float*  sint = (float*)alloc((size_t)T_SEQ * 32 * 4);
    float*  opart = (float*)alloc((size_t)2048 * 2048 * 4);  // 2048 slots x 32q x 64d fp32
    float*  lpart = (float*)alloc((size_t)2048 * 128 * 4);   // 2048 slots x 2j x 64 lanes

    convert_kernel<<<8192, 256, 0, stream>>>(x, wq, wk, wv, wo, xb, wqb, wkb, wvb, wob);
    rope_kernel<<<256, 256, 0, stream>>>(cost, sint);
    gemm_fused<<<dim3(32, 8, 3), 256, 0, stream>>>(xb, wqb, wkb, wvb, qb, kb, vtb, cost, sint, nullptr, 0);
    attn_kernel<<<dim3(32, 96), 64, 0, stream>>>(qb, kb, vtb, ob, opart, lpart);
    combine_kernel<<<dim3(32, 32), 256, 0, stream>>>(opart, lpart, ob);
    gemm_fused<<<dim3(32, 8, 1), 256, 0, stream>>>(ob, wob, nullptr, nullptr, nullptr, nullptr, nullptr,
                                                   cost, sint, out, 3);
}

// Round 6
// 199.719 us; speedup vs baseline: 1.1136x; 1.1136x over previous
//
#include <hip/hip_runtime.h>
#include <hip/hip_bf16.h>

typedef __bf16 bf16_t;
typedef __bf16 bf16x8 __attribute__((ext_vector_type(8)));
typedef float f32x4 __attribute__((ext_vector_type(4)));
typedef short short4v __attribute__((ext_vector_type(4)));
typedef unsigned int uint2v __attribute__((ext_vector_type(2)));

#define D_MODEL 1024
#define T_SEQ 2048
#define NH 16
#define DKD 64
#define X_ELEMS (4194304u)   // 2*2048*1024
#define W_ELEMS (1048576u)   // 1024*1024
// 0.125 * log2(e): folds the 1/sqrt(dk) scale AND the exp->exp2 conversion into Q
#define Q_SCALE 0.18033688011112042f

__device__ __forceinline__ void async16(const bf16_t* g, bf16_t* l) {
    __builtin_amdgcn_global_load_lds((const __attribute__((address_space(1))) void*)g,
                                     (__attribute__((address_space(3))) void*)l, 16, 0, 0);
}

__device__ __forceinline__ unsigned ldsa(const bf16_t* p) {
    return (unsigned)(size_t)(const __attribute__((address_space(3))) bf16_t*)p;
}

// ---------------- fp32 -> bf16 conversion for x + 4 weights ----------------
__global__ __launch_bounds__(256) void convert_kernel(
    const float* __restrict__ x, const float* __restrict__ wq,
    const float* __restrict__ wk, const float* __restrict__ wv,
    const float* __restrict__ wo,
    bf16_t* __restrict__ xb, bf16_t* __restrict__ wqb, bf16_t* __restrict__ wkb,
    bf16_t* __restrict__ wvb, bf16_t* __restrict__ wob)
{
    size_t idx = ((size_t)blockIdx.x * 256 + threadIdx.x) * 4;
    const float* src; bf16_t* dst; size_t off;
    if (idx < X_ELEMS) { src = x; dst = xb; off = idx; }
    else {
        size_t r = idx - X_ELEMS;
        unsigned w = (unsigned)(r >> 20);
        off = r & (W_ELEMS - 1);
        src = (w == 0) ? wq : (w == 1) ? wk : (w == 2) ? wv : wo;
        dst = (w == 0) ? wqb : (w == 1) ? wkb : (w == 2) ? wvb : wob;
    }
    float4 v = *(const float4*)(src + off);
    union { bf16_t b[4]; short4v s; } u;
    u.b[0] = (bf16_t)v.x; u.b[1] = (bf16_t)v.y;
    u.b[2] = (bf16_t)v.z; u.b[3] = (bf16_t)v.w;
    *(short4v*)(dst + off) = u.s;
}

// ---------------- RoPE cos/sin tables: [T][32] ----------------
__global__ __launch_bounds__(256) void rope_kernel(float* __restrict__ cost, float* __restrict__ sint)
{
    int idx = blockIdx.x * 256 + threadIdx.x;  // < 2048*32
    int t = idx >> 5, i = idx & 31;
    float inv = expf(-0.28782313662425572f * (float)i);  // 10000^(-i/32)
    float ang = (float)t * inv;
    float s, c;
    sincosf(ang, &s, &c);
    cost[idx] = c; sint[idx] = s;
}

// ---------------- GEMM C[m,n] = sum_k A[m,k]*W[n,k]  (m97 structure) ----------------
// mode 0: Q out (rope, *Q_SCALE, (B,H,T,DK) bf16)   mode 1: K out (rope, (B,H,T,DK) bf16)
// mode 2: V^T out (B,H,DK,T) bf16 — SWAPPED operands so C/D col (lane&15) = token.
// mode 3: plain fp32 out [M,N]
__global__ __launch_bounds__(256) void gemm_fused(
    const bf16_t* __restrict__ A,
    const bf16_t* __restrict__ W0, const bf16_t* __restrict__ W1, const bf16_t* __restrict__ W2,
    bf16_t* __restrict__ qout, bf16_t* __restrict__ kout, bf16_t* __restrict__ vout,
    const float* __restrict__ cost, const float* __restrict__ sint,
    float* __restrict__ fout, int modeBase)
{
    const int K = 1024;
    __shared__ bf16_t As[128 * 32];
    __shared__ bf16_t Bs[128 * 32];
    const int tid = threadIdx.x;
    const int wave = tid >> 6, lane = tid & 63;
    const int quad = lane >> 4, l16 = lane & 15;
    const int m0 = blockIdx.x * 128;
    const int n0 = blockIdx.y * 128;
    const int wm = (wave >> 1) * 64, wn = (wave & 1) * 64;
    const int mode = modeBase + blockIdx.z;
    const bf16_t* W = (mode == 1) ? W1 : (mode == 2) ? W2 : W0;

    const bf16_t* Afrag = (mode == 2) ? Bs : As;
    const bf16_t* Bfrag = (mode == 2) ? As : Bs;
    const int aoff = (mode == 2) ? wn : wm;
    const int boff = (mode == 2) ? wm : wn;

    const f32x4 fzero = {0.f, 0.f, 0.f, 0.f};
    f32x4 acc[4][4];
    #pragma unroll
    for (int i = 0; i < 4; ++i)
        #pragma unroll
        for (int j = 0; j < 4; ++j) acc[i][j] = fzero;

    for (int k0 = 0; k0 < K; k0 += 32) {
        __syncthreads();
        #pragma unroll
        for (int c = 0; c < 2; ++c) {
            int G = c * 256 + tid;
            int row = G >> 2, go = G & 3;
            async16(A + (size_t)(m0 + row) * K + (k0 + go * 8), As + (size_t)(c * 256 + wave * 64) * 8);
            async16(W + (size_t)(n0 + row) * K + (k0 + go * 8), Bs + (size_t)(c * 256 + wave * 64) * 8);
        }
        __syncthreads();
        bf16x8 af[4], bfv[4];
        #pragma unroll
        for (int mi = 0; mi < 4; ++mi)
            af[mi] = *(const bf16x8*)(Afrag + (aoff + mi * 16 + l16) * 32 + quad * 8);
        #pragma unroll
        for (int ni = 0; ni < 4; ++ni)
            bfv[ni] = *(const bf16x8*)(Bfrag + (boff + ni * 16 + l16) * 32 + quad * 8);
        #pragma unroll
        for (int mi = 0; mi < 4; ++mi)
            #pragma unroll
            for (int ni = 0; ni < 4; ++ni)
                acc[mi][ni] = __builtin_amdgcn_mfma_f32_16x16x32_bf16(af[mi], bfv[ni], acc[mi][ni], 0, 0, 0);
    }

    #pragma unroll
    for (int mi = 0; mi < 4; ++mi) {
        #pragma unroll
        for (int ni = 0; ni < 4; ++ni) {
            #pragma unroll
            for (int reg = 0; reg < 4; ++reg) {
                float v = acc[mi][ni][reg];
                if (mode == 2) {
                    int f   = n0 + wn + mi * 16 + quad * 4 + reg;
                    int tok = m0 + wm + ni * 16 + l16;
                    int t = tok & (T_SEQ - 1), b = tok >> 11;
                    int h = f >> 6, dk = f & 63;
                    vout[(((size_t)b * NH + h) * DKD + dk) * T_SEQ + t] = (bf16_t)v;
                } else {
                    int row = m0 + wm + mi * 16 + quad * 4 + reg;
                    int col = n0 + wn + ni * 16 + l16;
                    if (mode == 3) {
                        fout[(size_t)row * D_MODEL + col] = v;
                    } else {
                        int t = row & (T_SEQ - 1), b = row >> 11;
                        int h = col >> 6, dk = col & 63;
                        float vp = __shfl_xor(v, 1);
                        int fi = dk >> 1;
                        float c = cost[t * 32 + fi], s = sint[t * 32 + fi];
                        float r = (dk & 1) ? (vp * s + v * c) : (v * c - vp * s);
                        if (mode == 0) r *= Q_SCALE;   // fold 1/sqrt(dk)*log2e into Q
                        bf16_t* dst = (mode == 0) ? qout : kout;
                        dst[(((size_t)b * NH + h) * T_SEQ + t) * DKD + dk] = (bf16_t)r;
                    }
                }
            }
        }
    }
}

// ---------------- flash attention: split-K balanced, V staged via LDS ----------------
// Round-3 post-mortem: VGPR=124 < persistent demand (~144) proved the allocator
// SANK the V register prefetch next to PV -> full L2/L3 latency exposed per tile
// (per-tile 5.3k cyc, 85% stall, all pipes idle). Fix: V lives in a per-wave
// 2x8KB LDS double-buffer staged with global_load_lds (prefetch has ZERO VGPR
// cost -> cannot be sunk). XOR-swizzle (slot^(row&7)) applied by pre-swizzling
// the GLOBAL source (gllds dest must be linear), sigma(quad) folded into the
// swizzled ds_read slots. PV reads are inline-asm ds_read_b128 + lgkmcnt(0),
// BRACKETED by sched_barrier(0) on BOTH sides: the one BEFORE pins the ds_read
// after the QK cluster (and thus after the compiler's K-reg vmcnt wait — the
// wait that transitively guarantees V(kt)'s older LDS-DMA writes retired,
// since vmcnt retires in order and V(kt) staging issues before K(kt) loads);
// the one AFTER stops MFMAs from hoisting past the lgkmcnt (rule #18).
__global__ __launch_bounds__(64, 2) void attn_kernel(
    const bf16_t* __restrict__ Q, const bf16_t* __restrict__ Kb,
    const bf16_t* __restrict__ Vt, bf16_t* __restrict__ O,
    float* __restrict__ Opart, float* __restrict__ Lpart)
{
    __shared__ bf16_t Vs[2][4096];   // 16 KB: two 64d x 64key V^T tiles, swizzled
    const int lane = threadIdx.x;
    const int quad = lane >> 4, l16 = lane & 15;
    const int sig = ((quad & 1) << 1) | (quad >> 1);   // sigma(quad)
    const int m7 = l16 & 7;
    const int bh = blockIdx.x;
    const int u = blockIdx.y;
    int y, ktlo, kthi;
    if (u < 32) { y = u + 32; ktlo = 0; kthi = 16; }
    else { y = 95 - u; ktlo = (u < 64) ? 16 : 0; kthi = (y * 32 + 95) >> 6; }
    const int qw = y * 32;

    const bf16_t* kbase = Kb + (size_t)bh * T_SEQ * DKD;
    const bf16_t* vbase = Vt + (size_t)bh * DKD * T_SEQ;

    // V staging source (lane-constant part): call c covers rows 8c..8c+7;
    // lane l -> row 8c+(l>>3), source slot (l&7)^(l>>3)  [inverse swizzle]
    const int vrow = lane >> 3;
    const bf16_t* vsrc = vbase + (size_t)vrow * T_SEQ + (((lane & 7) ^ vrow) * 8);

    // swizzled ds_read byte offsets (lane-constant): row l16 (+di*16 via imm),
    // slot sig^(l16&7) for keys [0,32), (sig+4)^(l16&7) for keys [32,64)
    const unsigned o0 = (unsigned)((l16 * 64 + ((sig ^ m7) * 8)) << 1);
    const unsigned o1 = (unsigned)((l16 * 64 + (((sig + 4) ^ m7) * 8)) << 1);
    const unsigned vbase0 = ldsa(Vs[0]);
    const unsigned vbase1 = ldsa(Vs[1]);

    // Q^T B-frags: n=l16 (query), k=quad*8+j (+32)
    bf16x8 qf[2][2];
    #pragma unroll
    for (int j = 0; j < 2; ++j) {
        const bf16_t* qp = Q + ((size_t)bh * T_SEQ + qw + j * 16 + l16) * DKD;
        qf[j][0] = *(const bf16x8*)(qp + quad * 8);
        qf[j][1] = *(const bf16x8*)(qp + 32 + quad * 8);
    }
    const f32x4 fzero = {0.f, 0.f, 0.f, 0.f};
    f32x4 oacc[2][4];
    #pragma unroll
    for (int j = 0; j < 2; ++j)
        #pragma unroll
        for (int i = 0; i < 4; ++i) oacc[j][i] = fzero;
    float lsum[2] = {0.f, 0.f};   // in-lane partial softmax denominator

    // prologue: stage V(ktlo) into Vs[0] FIRST, then load K(ktlo) into regs.
    #pragma unroll
    for (int c = 0; c < 8; ++c)
        async16(vsrc + (ktlo * 64) + c * 16384, &Vs[0][0] + c * 512);
    __builtin_amdgcn_sched_barrier(0);

    bf16x8 ka[4][2], kb2[4][2];
    #pragma unroll
    for (int fi = 0; fi < 4; ++fi) {
        const bf16_t* kr = kbase + (size_t)(ktlo * 64 + fi * 16 + l16) * DKD + quad * 8;
        ka[fi][0] = *(const bf16x8*)(kr);
        ka[fi][1] = *(const bf16x8*)(kr + 32);
    }

#define ATT_TILE(KC, KN, VRB, VST) do { \
    const int k0 = kt * 64; \
    if (kt + 1 < kthi) { \
        _Pragma("unroll") \
        for (int c = 0; c < 8; ++c) \
            async16(vsrc + (k0 + 64) + c * 16384, (VST) + c * 512); \
    } \
    __builtin_amdgcn_sched_barrier(0); \
    if (kt + 1 < kthi) { \
        _Pragma("unroll") \
        for (int fi = 0; fi < 4; ++fi) { \
            const bf16_t* kr = kbase + (size_t)(k0 + 64 + fi * 16 + l16) * DKD + quad * 8; \
            KN[fi][0] = *(const bf16x8*)(kr); \
            KN[fi][1] = *(const bf16x8*)(kr + 32); \
        } \
    } \
    _Pragma("unroll") \
    for (int j = 0; j < 2; ++j) { \
        if (k0 > qw + j * 16 + 15) continue;   /* q-tile fully masked */ \
        const int qcol = qw + j * 16 + l16; \
        f32x4 s[4]; \
        _Pragma("unroll") \
        for (int fi = 0; fi < 4; ++fi) { \
            f32x4 z = fzero; \
            z = __builtin_amdgcn_mfma_f32_16x16x32_bf16(KC[fi][0], qf[j][0], z, 0, 0, 0); \
            z = __builtin_amdgcn_mfma_f32_16x16x32_bf16(KC[fi][1], qf[j][1], z, 0, 0, 0); \
            s[fi] = z; \
        } \
        if (k0 + 63 > qw + j * 16) { \
            _Pragma("unroll") \
            for (int fi = 0; fi < 4; ++fi) \
                _Pragma("unroll") \
                for (int reg = 0; reg < 4; ++reg) { \
                    int key = k0 + fi * 16 + quad * 4 + reg; \
                    s[fi][reg] = (key > qcol) ? -__builtin_inff() : s[fi][reg]; \
                } \
        } \
        float sm = 0.f; \
        _Pragma("unroll") \
        for (int fi = 0; fi < 4; ++fi) \
            _Pragma("unroll") \
            for (int reg = 0; reg < 4; ++reg) { \
                float p = __builtin_amdgcn_exp2f(s[fi][reg]); \
                s[fi][reg] = p; sm += p; \
            } \
        lsum[j] += sm; \
        unsigned wv[4][2]; \
        _Pragma("unroll") \
        for (int fi = 0; fi < 4; ++fi) { \
            asm("v_cvt_pk_bf16_f32 %0, %1, %2" : "=v"(wv[fi][0]) : "v"(s[fi][0]), "v"(s[fi][1])); \
            asm("v_cvt_pk_bf16_f32 %0, %1, %2" : "=v"(wv[fi][1]) : "v"(s[fi][2]), "v"(s[fi][3])); \
        } \
        uint2v r0 = __builtin_amdgcn_permlane16_swap(wv[0][0], wv[1][0], false, false); \
        uint2v r1 = __builtin_amdgcn_permlane16_swap(wv[0][1], wv[1][1], false, false); \
        uint2v r2 = __builtin_amdgcn_permlane16_swap(wv[2][0], wv[3][0], false, false); \
        uint2v r3 = __builtin_amdgcn_permlane16_swap(wv[2][1], wv[3][1], false, false); \
        union { unsigned uu[4]; bf16x8 v; } p0, p1; \
        p0.uu[0] = r0[0]; p0.uu[1] = r1[0]; p0.uu[2] = r0[1]; p0.uu[3] = r1[1]; \
        p1.uu[0] = r2[0]; p1.uu[1] = r3[0]; p1.uu[2] = r2[1]; p1.uu[3] = r3[1]; \
        /* V frags from swizzled LDS: w{di}a = key slot sig, w{di}b = sig+4 */ \
        const unsigned aA = (VRB) + o0, aB = (VRB) + o1; \
        bf16x8 w0a, w0b, w1a, w1b, w2a, w2b, w3a, w3b; \
        __builtin_amdgcn_sched_barrier(0); \
        asm volatile( \
            "ds_read_b128 %0, %8 offset:0\n\t" \
            "ds_read_b128 %1, %9 offset:0\n\t" \
            "ds_read_b128 %2, %8 offset:2048\n\t" \
            "ds_read_b128 %3, %9 offset:2048\n\t" \
            "ds_read_b128 %4, %8 offset:4096\n\t" \
            "ds_read_b128 %5, %9 offset:4096\n\t" \
            "ds_read_b128 %6, %8 offset:6144\n\t" \
            "ds_read_b128 %7, %9 offset:6144\n\t" \
            "s_waitcnt lgkmcnt(0)" \
            : "=&v"(w0a), "=&v"(w0b), "=&v"(w1a), "=&v"(w1b), \
              "=&v"(w2a), "=&v"(w2b), "=&v"(w3a), "=&v"(w3b) \
            : "v"(aA), "v"(aB)); \
        __builtin_amdgcn_sched_barrier(0); \
        oacc[j][0] = __builtin_amdgcn_mfma_f32_16x16x32_bf16(w0a, p0.v, oacc[j][0], 0, 0, 0); \
        oacc[j][0] = __builtin_amdgcn_mfma_f32_16x16x32_bf16(w0b, p1.v, oacc[j][0], 0, 0, 0); \
        oacc[j][1] = __builtin_amdgcn_mfma_f32_16x16x32_bf16(w1a, p0.v, oacc[j][1], 0, 0, 0); \
        oacc[j][1] = __builtin_amdgcn_mfma_f32_16x16x32_bf16(w1b, p1.v, oacc[j][1], 0, 0, 0); \
        oacc[j][2] = __builtin_amdgcn_mfma_f32_16x16x32_bf16(w2a, p0.v, oacc[j][2], 0, 0, 0); \
        oacc[j][2] = __builtin_amdgcn_mfma_f32_16x16x32_bf16(w2b, p1.v, oacc[j][2], 0, 0, 0); \
        oacc[j][3] = __builtin_amdgcn_mfma_f32_16x16x32_bf16(w3a, p0.v, oacc[j][3], 0, 0, 0); \
        oacc[j][3] = __builtin_amdgcn_mfma_f32_16x16x32_bf16(w3b, p1.v, oacc[j][3], 0, 0, 0); \
    } \
} while (0)

    bool flip = false;
    for (int kt = ktlo; kt < kthi; ++kt) {
        if (!flip) { ATT_TILE(ka, kb2, vbase0, &Vs[1][0]); }
        else       { ATT_TILE(kb2, ka, vbase1, &Vs[0][0]); }
        flip = !flip;
    }
#undef ATT_TILE

    if (u >= 64) {
        // single-chunk: cross-quad l reduction, scale, store bf16 directly
        const int b = bh >> 4, h = bh & 15;
        #pragma unroll
        for (int j = 0; j < 2; ++j) {
            float l = lsum[j];
            l += __shfl_xor(l, 16);
            l += __shfl_xor(l, 32);
            float rl = 1.0f / l;
            int q = qw + j * 16 + l16;
            #pragma unroll
            for (int di = 0; di < 4; ++di) {
                union { bf16_t hh[4]; unsigned long long u64; } ok;
                #pragma unroll
                for (int reg = 0; reg < 4; ++reg) ok.hh[reg] = (bf16_t)(oacc[j][di][reg] * rl);
                int d = di * 16 + quad * 4;
                *(unsigned long long*)(O + ((size_t)b * T_SEQ + q) * D_MODEL + h * DKD + d) = ok.u64;
            }
        }
    } else {
        // partial: raw fp32 oacc + per-lane lsum to workspace (coalesced 16B stores)
        const int yy = y - 32;
        const int chunk = (ktlo == 16) ? 1 : 0;
        const size_t slot = ((size_t)bh * 32 + yy) * 2 + chunk;
        float* op = Opart + slot * 2048;
        #pragma unroll
        for (int j = 0; j < 2; ++j) {
            Lpart[slot * 128 + j * 64 + lane] = lsum[j];
            #pragma unroll
            for (int di = 0; di < 4; ++di)
                *(f32x4*)(op + ((size_t)(j * 4 + di) * 64 + lane) * 4) = oacc[j][di];
        }
    }
}

// ---------------- combine: O = (O_c0 + O_c1) / (l_c0 + l_c1), upper half only ----------------
__global__ __launch_bounds__(256) void combine_kernel(
    const float* __restrict__ Opart, const float* __restrict__ Lpart, bf16_t* __restrict__ O)
{
    const int bh = blockIdx.x, yy = blockIdx.y;
    const int t = threadIdx.x;
    const int ql = t >> 3;             // 0..31 local query
    const int d0 = (t & 7) * 8;        // 0,8,...,56
    const int j = ql >> 4, l16 = ql & 15;
    const size_t a = (size_t)bh * 32 + yy;
    const float* A0 = Opart + a * 2 * 2048;
    const float* A1 = A0 + 2048;
    const float* L = Lpart + a * 2 * 128 + j * 64 + l16;
    float l = 0.f;
    #pragma unroll
    for (int q = 0; q < 4; ++q) l += L[q * 16] + L[128 + q * 16];
    const float rl = 1.0f / l;
    const int di = d0 >> 4;
    const int quad0 = (d0 & 15) >> 2;  // 0 or 2
    union { bf16_t h[8]; bf16x8 v; } ov;
    #pragma unroll
    for (int g = 0; g < 2; ++g) {
        const int off = ((j * 4 + di) * 64 + (quad0 + g) * 16 + l16) * 4;
        f32x4 x0 = *(const f32x4*)(A0 + off);
        f32x4 x1 = *(const f32x4*)(A1 + off);
        #pragma unroll
        for (int reg = 0; reg < 4; ++reg)
            ov.h[g * 4 + reg] = (bf16_t)((x0[reg] + x1[reg]) * rl);
    }
    const int b = bh >> 4, h = bh & 15;
    const int q = 1024 + yy * 32 + ql;
    *(bf16x8*)(O + ((size_t)b * T_SEQ + q) * D_MODEL + h * DKD + d0) = ov.v;
}

extern "C" void kernel_launch(void* const* d_in, const int* in_sizes, int n_in,
                              void* d_out, int out_size, void* d_ws, size_t ws_size,
                              hipStream_t stream)
{
    const float* x  = (const float*)d_in[0];
    const float* wq = (const float*)d_in[1];
    const float* wk = (const float*)d_in[2];
    const float* wv = (const float*)d_in[3];
    const float* wo = (const float*)d_in[4];
    float* out = (float*)d_out;

    char* ws = (char*)d_ws;
    size_t off = 0;
    auto alloc = [&](size_t bytes) -> void* {
        void* p = ws + off; off += (bytes + 255) & ~(size_t)255; return p;
    };
    bf16_t* xb   = (bf16_t*)alloc((size_t)X_ELEMS * 2);
    bf16_t* wqb  = (bf16_t*)alloc((size_t)W_ELEMS * 2);
    bf16_t* wkb  = (bf16_t*)alloc((size_t)W_ELEMS * 2);
    bf16_t* wvb  = (bf16_t*)alloc((size_t)W_ELEMS * 2);
    bf16_t* wob  = (bf16_t*)alloc((size_t)W_ELEMS * 2);
    bf16_t* qb   = (bf16_t*)alloc((size_t)X_ELEMS * 2);
    bf16_t* kb   = (bf16_t*)alloc((size_t)X_ELEMS * 2);
    bf16_t* vtb  = (bf16_t*)alloc((size_t)X_ELEMS * 2);
    bf16_t* ob   = (bf16_t*)alloc((size_t)X_ELEMS * 2);
    float*  cost = (float*)alloc((size_t)T_SEQ * 32 * 4);
    float*  sint = (float*)alloc((size_t)T_SEQ * 32 * 4);
    float*  opart = (float*)alloc((size_t)2048 * 2048 * 4);  // 2048 slots x 32q x 64d fp32
    float*  lpart = (float*)alloc((size_t)2048 * 128 * 4);   // 2048 slots x 2j x 64 lanes

    convert_kernel<<<8192, 256, 0, stream>>>(x, wq, wk, wv, wo, xb, wqb, wkb, wvb, wob);
    rope_kernel<<<256, 256, 0, stream>>>(cost, sint);
    gemm_fused<<<dim3(32, 8, 3), 256, 0, stream>>>(xb, wqb, wkb, wvb, qb, kb, vtb, cost, sint, nullptr, 0);
    attn_kernel<<<dim3(32, 96), 64, 0, stream>>>(qb, kb, vtb, ob, opart, lpart);
    combine_kernel<<<dim3(32, 32), 256, 0, stream>>>(opart, lpart, ob);
    gemm_fused<<<dim3(32, 8, 1), 256, 0, stream>>>(ob, wob, nullptr, nullptr, nullptr, nullptr, nullptr,
                                                   cost, sint, out, 3);
}